// Round 11
// baseline (109.278 us; speedup 1.0000x reference)
//
#include <hip/hip_runtime.h>

#define Nn 256
#define Cc 128
#define Pp 275
#define Dd 128

typedef unsigned int u32;
typedef unsigned short u16;
typedef float f32x4 __attribute__((ext_vector_type(4)));
typedef short bf16x8 __attribute__((ext_vector_type(8)));

__device__ __forceinline__ float bf2f(u16 h) {
    return __uint_as_float(((u32)h) << 16);
}
__device__ __forceinline__ u16 f2bf(float f) {
    u32 u = __float_as_uint(f);
    return (u16)((u + 0x7fffu + ((u >> 16) & 1u)) >> 16);
}

// async global->LDS, 16 B per lane; LDS dest = wave-uniform base + lane*16
__device__ __forceinline__ void gload16(const float* g, float* l) {
    __builtin_amdgcn_global_load_lds(
        (const __attribute__((address_space(1))) void*)g,
        (__attribute__((address_space(3))) void*)l, 16, 0, 0);
}

// ---------------- K1: bias_t / bias_p (N x D) + f->bf16 + Wl^T bf16 ----------------
__global__ __launch_bounds__(256) void bias_kernel(
    const float* __restrict__ m_t, const float* __restrict__ m_p,
    const float* __restrict__ c_t, const float* __restrict__ c_p,
    const float* __restrict__ W, const float* __restrict__ b,
    const float* __restrict__ f,
    float* __restrict__ bias_t, float* __restrict__ bias_p,
    u16* __restrict__ f_bf, u16* __restrict__ WlT)
{
    int idx = blockIdx.x * 256 + threadIdx.x;   // N*D = 32768
    int n = idx >> 7, d = idx & 127;
    float at = 0.f, ap = 0.f;
#pragma unroll 8
    for (int k = 0; k < 64; ++k) {
        float wm = W[(128 + k) * 128 + d];
        float wc = W[(192 + k) * 128 + d];
        at = fmaf(m_t[n * 64 + k], wm, at);
        at = fmaf(c_t[n * 64 + k], wc, at);
        ap = fmaf(m_p[n * 64 + k], wm, ap);
        ap = fmaf(c_p[n * 64 + k], wc, ap);
    }
    float bb = b[d];
    bias_t[idx] = at + bb;
    bias_p[idx] = ap + bb;
    f_bf[idx] = f2bf(f[idx]);
    if (idx < 16384) {                 // WlT[d][c] = Wl[c][d]
        int dd = idx >> 7, cc = idx & 127;
        WlT[idx] = f2bf(W[cc * 128 + dd]);
    }
}

// ---------------- K2: join via global_load_lds double-buffer (m97 pattern) ---------
// grid (2, 256): half = blockIdx.x (p-tiles half*9..half*9+8), n = blockIdx.y.
// 512 thr = 8 waves; wave w: pass = w&1 (0:x_t->pred, 1:x_p->pos), dt = {w>>1, w>>1+4}.
// Tile 17 re-anchored at p0=259 (overlap rows recompute identical values).
__global__ __launch_bounds__(512) void join_gl_kernel(
    const float* __restrict__ x_t, const float* __restrict__ x_p,
    const u16* __restrict__ WlT,
    const float* __restrict__ bias_t, const float* __restrict__ bias_p,
    u16* __restrict__ pred, u16* __restrict__ pos)
{
    __shared__ u16 wlds[128 * 128];     // 32 KB swizzled WlT
    __shared__ float xbuf[2][4096];     // 2 x 16 KB: [0..2047]=x_t tile, [2048..]=x_p tile
    const int tid = threadIdx.x;
    const int half = blockIdx.x;
    const int n = blockIdx.y;
    const int w = tid >> 6;
    const int l = tid & 63;
    const int g = l >> 4;

    {   // stage WlT swizzled: 2048 uint4 over 512 threads
        const uint4* src = reinterpret_cast<const uint4*>(WlT);
#pragma unroll
        for (int it = 0; it < 4; ++it) {
            int j = tid + 512 * it;
            int row = j >> 4;
            int colb = (j & 15) << 4;
            uint4 v = src[j];
            *reinterpret_cast<uint4*>((char*)wlds + row * 256 + (colb ^ ((row & 7) << 4))) = v;
        }
    }

    const float* xbt = x_t + (size_t)n * (Cc * Pp);
    const float* xbp = x_p + (size_t)n * (Cc * Pp);

    const int dt0 = w >> 1;
    const float* bias = (w & 1) ? bias_p : bias_t;
    u16* outp = (w & 1) ? pos : pred;
    float bv0 = bias[n * 128 + dt0 * 16 + (l & 15)];
    float bv1 = bias[n * 128 + (dt0 + 4) * 16 + (l & 15)];

    // staging address pieces: wave block = 16 c-rows, lane covers (c = w*16 + l>>2, p-quad l&3)
    const int sc = (w << 4) + (l >> 2);
    const int sp = (l & 3) << 2;

    {   // prologue: stage tile half*9 into buf 0
        const int t0 = half * 9;
        const int p0 = (t0 < 17) ? t0 * 16 : 259;
        const size_t go = (size_t)sc * Pp + p0 + sp;
        gload16(xbt + go, &xbuf[0][w * 256]);
        gload16(xbp + go, &xbuf[0][2048 + w * 256]);
    }
    __syncthreads();

    int ib = 0;
    for (int tt = 0; tt < 9; ++tt) {
        const int tcur = half * 9 + tt;
        const int p0 = (tcur < 17) ? tcur * 16 : 259;
        if (tt < 8) {                    // stage next tile into other buffer
            const int tn = tcur + 1;
            const int pn = (tn < 17) ? tn * 16 : 259;
            const size_t go = (size_t)sc * Pp + pn + sp;
            gload16(xbt + go, &xbuf[ib ^ 1][w * 256]);
            gload16(xbp + go, &xbuf[ib ^ 1][2048 + w * 256]);
        }

        // A-frags: 32 scalar LDS reads (e rotated by g for bank spread) + convert
        const float* xb = &xbuf[ib][(w & 1) * 2048];
        bf16x8 A[4];
#pragma unroll
        for (int kk = 0; kk < 4; ++kk) {
            bf16x8 a;
#pragma unroll
            for (int j = 0; j < 8; ++j) {
                const int e = (j + g) & 7;
                const int c = kk * 32 + g * 8 + e;
                float v = xb[((c >> 4) << 8) + ((c & 15) << 4) + (l & 15)];
                a[e] = (short)f2bf(v);
            }
            A[kk] = a;
        }

#pragma unroll
        for (int i = 0; i < 2; ++i) {
            const int dt = dt0 + i * 4;
            bf16x8 B[4];
            const int row = dt * 16 + (l & 15);
#pragma unroll
            for (int kk = 0; kk < 4; ++kk) {
                int cbyte = kk * 64 + (g << 4);
                B[kk] = *reinterpret_cast<const bf16x8*>(
                    (const char*)wlds + row * 256 + (cbyte ^ ((row & 7) << 4)));
            }
            f32x4 acc = {0.f, 0.f, 0.f, 0.f};
#pragma unroll
            for (int kk = 0; kk < 4; ++kk)
                acc = __builtin_amdgcn_mfma_f32_16x16x32_bf16(A[kk], B[kk], acc, 0, 0, 0);
            const int d = dt * 16 + (l & 15);
            const float bv = i ? bv1 : bv0;
#pragma unroll
            for (int r = 0; r < 4; ++r) {
                const int p = p0 + g * 4 + r;          // always < Pp by construction
                outp[((size_t)p * Nn + n) * Dd + d] = f2bf(acc[r] + bv);
            }
        }

        __syncthreads();
        ib ^= 1;
    }
}

// ---------------- K3: MFMA logits + fixed-shift LSE - diag (R8 best form) ----------
// grid (2, Pp): sel = blockIdx.x; 512 threads = 8 waves; wave w rows w*32..+31.
__global__ __launch_bounds__(512) void logits_mfma_kernel(
    const u16* __restrict__ f_bf,
    const u16* __restrict__ pred, const u16* __restrict__ pos,
    float* __restrict__ partial)
{
    __shared__ u16 lds[Nn * Dd];   // 64 KB swizzled pos[p] tile
    const int tid = threadIdx.x;
    const int sel = blockIdx.x;
    const int p = blockIdx.y;
    const int w = tid >> 6;
    const int l = tid & 63;
    const int r0 = w * 32;

    {
        const uint4* src = reinterpret_cast<const uint4*>(pos + (size_t)p * (Nn * Dd));
#pragma unroll
        for (int it = 0; it < 8; ++it) {
            int j = tid + 512 * it;
            int row = j >> 4;
            int colb = (j & 15) << 4;
            uint4 v = src[j];
            *reinterpret_cast<uint4*>((char*)lds + row * 256 + (colb ^ ((row & 7) << 4))) = v;
        }
    }

    const u16* Abase = sel ? (pred + (size_t)p * (Nn * Dd)) : f_bf;
    bf16x8 A[2][4];
    {
        const int arow = l & 15;
        const int acol = (l >> 4) << 4;
#pragma unroll
        for (int rt = 0; rt < 2; ++rt)
#pragma unroll
            for (int kk = 0; kk < 4; ++kk) {
                const char* ap = (const char*)Abase
                               + (size_t)(r0 + rt * 16 + arow) * 256 + kk * 64 + acol;
                A[rt][kk] = *reinterpret_cast<const bf16x8*>(ap);
            }
    }

    __syncthreads();

    const float L2E = 1.4426950408889634f;
    float s_[2][4];
    float dg[2][4];
#pragma unroll
    for (int rt = 0; rt < 2; ++rt)
#pragma unroll
        for (int r = 0; r < 4; ++r) { s_[rt][r] = 0.f; dg[rt][r] = 0.f; }

    const int mcol = l & 15;
    const int bcol = (l >> 4) << 4;

    for (int ct = 0; ct < 16; ++ct) {
        bf16x8 B[4];
        const int mrow = ct * 16 + mcol;
#pragma unroll
        for (int kk = 0; kk < 4; ++kk) {
            int cb = kk * 64 + bcol;
            B[kk] = *reinterpret_cast<const bf16x8*>(
                (const char*)lds + mrow * 256 + (cb ^ ((mrow & 7) << 4)));
        }
#pragma unroll
        for (int rt = 0; rt < 2; ++rt) {
            f32x4 acc = {0.f, 0.f, 0.f, 0.f};
#pragma unroll
            for (int kk = 0; kk < 4; ++kk)
                acc = __builtin_amdgcn_mfma_f32_16x16x32_bf16(A[rt][kk], B[kk], acc, 0, 0, 0);
            const bool isdg_ct = (ct == ((r0 >> 4) + rt));
#pragma unroll
            for (int r = 0; r < 4; ++r) {
                float v = acc[r];
                s_[rt][r] += __builtin_amdgcn_exp2f(fmaf(v, L2E, -64.f));
                if (isdg_ct && ((l & 15) == (((l >> 4) << 2) + r))) dg[rt][r] = v;
            }
        }
    }

    float local = 0.f;
#pragma unroll
    for (int rt = 0; rt < 2; ++rt)
#pragma unroll
        for (int r = 0; r < 4; ++r) {
            float s = s_[rt][r];
            s += __shfl_xor(s, 1);
            s += __shfl_xor(s, 2);
            s += __shfl_xor(s, 4);
            s += __shfl_xor(s, 8);
            if ((l & 15) == (((l >> 4) << 2) + r))
                local += 0.6931471805599453f * (64.f + __log2f(s)) - dg[rt][r];
        }

    __syncthreads();
    float* red = reinterpret_cast<float*>(lds);
    red[tid] = local;
    __syncthreads();
    for (int k = 256; k > 0; k >>= 1) {
        if (tid < k) red[tid] += red[tid + k];
        __syncthreads();
    }
    if (tid == 0) partial[p * 2 + sel] = red[0];
}

// ---------------- K4: deterministic final reduce ----------------
__global__ __launch_bounds__(256) void reduce_kernel(
    const float* __restrict__ partial, float* __restrict__ out)
{
    __shared__ float red[256];
    float s = 0.f;
    for (int i = threadIdx.x; i < 2 * Pp; i += 256) s += partial[i];
    red[threadIdx.x] = s;
    __syncthreads();
    for (int k = 128; k > 0; k >>= 1) {
        if (threadIdx.x < k) red[threadIdx.x] += red[threadIdx.x + k];
        __syncthreads();
    }
    if (threadIdx.x == 0) out[0] = red[0] * (1.0f / (Pp * (float)Nn));
}

extern "C" void kernel_launch(void* const* d_in, const int* in_sizes, int n_in,
                              void* d_out, int out_size, void* d_ws, size_t ws_size,
                              hipStream_t stream)
{
    const float* f   = (const float*)d_in[0];
    const float* x_t = (const float*)d_in[1];
    const float* x_p = (const float*)d_in[2];
    const float* m_t = (const float*)d_in[3];
    const float* m_p = (const float*)d_in[4];
    const float* c_t = (const float*)d_in[5];
    const float* c_p = (const float*)d_in[6];
    const float* W   = (const float*)d_in[7];
    const float* b   = (const float*)d_in[8];

    char* ws = (char*)d_ws;
    const size_t SLAB = (size_t)Pp * Nn * Dd;     // 9,011,200 elems

    float* bias_t = (float*)ws;                          // 131072 B
    float* bias_p = bias_t + Nn * Dd;                    // 131072 B
    u16* f_bf = (u16*)(ws + 262144);                     // 65536 B
    u16* WlT  = f_bf + Nn * Dd;                          // 32768 B
    u16* pred = (u16*)(ws + 360448);
    u16* pos  = pred + SLAB;
    float* partial = (float*)(pos + SLAB);

    bias_kernel<<<dim3(Nn * Dd / 256), 256, 0, stream>>>(m_t, m_p, c_t, c_p, W, b, f,
                                                         bias_t, bias_p, f_bf, WlT);
    join_gl_kernel<<<dim3(2, Nn), 512, 0, stream>>>(x_t, x_p, WlT, bias_t, bias_p,
                                                    pred, pos);
    logits_mfma_kernel<<<dim3(2, Pp), 512, 0, stream>>>(f_bf, pred, pos, partial);
    reduce_kernel<<<1, 256, 0, stream>>>(partial, (float*)d_out);
}

// Round 12
// 68.374 us; speedup vs baseline: 1.5982x; 1.5982x over previous
//
#include <hip/hip_runtime.h>

#define Nn 256
#define Cc 128
#define Pp 275
#define Dd 128

typedef unsigned int u32;
typedef unsigned short u16;
typedef float f32x4 __attribute__((ext_vector_type(4)));
typedef short bf16x8 __attribute__((ext_vector_type(8)));

__device__ __forceinline__ float bf2f(u16 h) {
    return __uint_as_float(((u32)h) << 16);
}
__device__ __forceinline__ u16 f2bf(float f) {
    u32 u = __float_as_uint(f);
    return (u16)((u + 0x7fffu + ((u >> 16) & 1u)) >> 16);
}

// ---------------- K1: bias_t / bias_p (N x D) + f->bf16 + Wl^T bf16 ----------------
__global__ __launch_bounds__(256) void bias_kernel(
    const float* __restrict__ m_t, const float* __restrict__ m_p,
    const float* __restrict__ c_t, const float* __restrict__ c_p,
    const float* __restrict__ W, const float* __restrict__ b,
    const float* __restrict__ f,
    float* __restrict__ bias_t, float* __restrict__ bias_p,
    u16* __restrict__ f_bf, u16* __restrict__ WlT)
{
    int idx = blockIdx.x * 256 + threadIdx.x;   // N*D = 32768
    int n = idx >> 7, d = idx & 127;
    float at = 0.f, ap = 0.f;
#pragma unroll 8
    for (int k = 0; k < 64; ++k) {
        float wm = W[(128 + k) * 128 + d];
        float wc = W[(192 + k) * 128 + d];
        at = fmaf(m_t[n * 64 + k], wm, at);
        at = fmaf(c_t[n * 64 + k], wc, at);
        ap = fmaf(m_p[n * 64 + k], wm, ap);
        ap = fmaf(c_p[n * 64 + k], wc, ap);
    }
    float bb = b[d];
    bias_t[idx] = at + bb;
    bias_p[idx] = ap + bb;
    f_bf[idx] = f2bf(f[idx]);
    if (idx < 16384) {                 // WlT[d][c] = Wl[c][d]
        int dd = idx >> 7, cc = idx & 127;
        WlT[idx] = f2bf(W[cc * 128 + dd]);
    }
}

// ---------------- K2: join — double-buffered reg-staged x, MFMA ----------------
// grid (2, 256): block = one n, 9 p-chunks of 16; 512 thr = 8 waves.
// Stage role: tid<256 -> x_t, else x_p; thread loads 2 c-rows x f32x4 (p-dir),
// converts, packs, writes transposed [p][c] bf16 (XOR-swizzled) into dbuf.
// Compute role: wave w = (pass w&1, dt {w>>1, w>>1+4}); A = ds_read_b128.
// Chunk 17 re-anchored at p0=259 (same-wave rewrite of identical values).
__global__ __launch_bounds__(512) void join_dbuf_kernel(
    const float* __restrict__ x_t, const float* __restrict__ x_p,
    const u16* __restrict__ WlT,
    const float* __restrict__ bias_t, const float* __restrict__ bias_p,
    u16* __restrict__ pred, u16* __restrict__ pos)
{
    __shared__ u16 wlds[128 * 128];        // 32 KB swizzled WlT
    __shared__ u16 xlds[2][2][16 * 128];   // 16 KB: [buf][pass][p][c] bf16
    const int tid = threadIdx.x;
    const int half = blockIdx.x;
    const int n = blockIdx.y;
    const int w = tid >> 6;
    const int l = tid & 63;
    const int g = l >> 4;

    {   // stage WlT swizzled: 2048 uint4 over 512 threads
        const uint4* src = reinterpret_cast<const uint4*>(WlT);
#pragma unroll
        for (int it = 0; it < 4; ++it) {
            int j = tid + 512 * it;
            int row = j >> 4;
            int colb = (j & 15) << 4;
            uint4 v = src[j];
            *reinterpret_cast<uint4*>((char*)wlds + row * 256 + (colb ^ ((row & 7) << 4))) = v;
        }
    }

    // ---- stage-role constants ----
    const int sq = tid & 255;
    const int spass = tid >> 8;                  // 0: x_t, 1: x_p
    const int sc0 = (sq >> 2) * 2;               // even c row pair
    const int sp4 = (sq & 3) << 2;               // p offset 0,4,8,12
    const float* sx = (spass ? x_p : x_t) + (size_t)n * (Cc * Pp);

    // ---- compute-role constants ----
    const int cpass = w & 1;
    const int dt0 = w >> 1;                      // dt in {dt0, dt0+4}
    const float* bias = cpass ? bias_p : bias_t;
    u16* outp = cpass ? pos : pred;
    const float bv0 = bias[n * 128 + dt0 * 16 + (l & 15)];
    const float bv1 = bias[n * 128 + (dt0 + 4) * 16 + (l & 15)];

    // prologue: stage chunk half*9 into buf 0
    {
        const int ch = half * 9;
        const int p0 = (ch < 17) ? ch * 16 : 259;
        const float* a = sx + (size_t)sc0 * Pp + p0 + sp4;
        f32x4 t0 = *reinterpret_cast<const f32x4*>(a);
        f32x4 t1 = *reinterpret_cast<const f32x4*>(a + Pp);
#pragma unroll
        for (int e = 0; e < 4; ++e) {
            const int row = sp4 + e;
            u32 pk = (u32)f2bf(t0[e]) | ((u32)f2bf(t1[e]) << 16);
            *reinterpret_cast<u32*>((char*)&xlds[0][spass][0]
                + row * 256 + ((sc0 * 2) ^ ((row & 7) << 4))) = pk;
        }
    }
    __syncthreads();

    int ib = 0;
    for (int tt = 0; tt < 9; ++tt) {
        const int ch = half * 9 + tt;
        const int p0 = (ch < 17) ? ch * 16 : 259;

        // issue next chunk's global loads (latency hides under compute below)
        f32x4 t0, t1;
        const bool have = (tt < 8);
        if (have) {
            const int chn = ch + 1;
            const int pn0 = (chn < 17) ? chn * 16 : 259;
            const float* a = sx + (size_t)sc0 * Pp + pn0 + sp4;
            t0 = *reinterpret_cast<const f32x4*>(a);
            t1 = *reinterpret_cast<const f32x4*>(a + Pp);
        }

        // compute current chunk from xlds[ib][cpass]
        const char* ab = (const char*)&xlds[ib][cpass][0];
        const int arow = l & 15;
        bf16x8 A[4];
#pragma unroll
        for (int kk = 0; kk < 4; ++kk)
            A[kk] = *reinterpret_cast<const bf16x8*>(
                ab + arow * 256 + ((kk * 64 + g * 16) ^ ((arow & 7) << 4)));

#pragma unroll
        for (int i = 0; i < 2; ++i) {
            const int dt = dt0 + i * 4;
            bf16x8 B[4];
            const int row = dt * 16 + (l & 15);
#pragma unroll
            for (int kk = 0; kk < 4; ++kk) {
                int cbyte = kk * 64 + (g << 4);
                B[kk] = *reinterpret_cast<const bf16x8*>(
                    (const char*)wlds + row * 256 + (cbyte ^ ((row & 7) << 4)));
            }
            f32x4 acc = {0.f, 0.f, 0.f, 0.f};
#pragma unroll
            for (int kk = 0; kk < 4; ++kk)
                acc = __builtin_amdgcn_mfma_f32_16x16x32_bf16(A[kk], B[kk], acc, 0, 0, 0);
            const int d = dt * 16 + (l & 15);
            const float bv = i ? bv1 : bv0;
#pragma unroll
            for (int r = 0; r < 4; ++r) {
                const int p = p0 + g * 4 + r;           // always < Pp by construction
                outp[((size_t)p * Nn + n) * Dd + d] = f2bf(acc[r] + bv);
            }
        }

        // write next chunk into the other buffer
        if (have) {
#pragma unroll
            for (int e = 0; e < 4; ++e) {
                const int row = sp4 + e;
                u32 pk = (u32)f2bf(t0[e]) | ((u32)f2bf(t1[e]) << 16);
                *reinterpret_cast<u32*>((char*)&xlds[ib ^ 1][spass][0]
                    + row * 256 + ((sc0 * 2) ^ ((row & 7) << 4))) = pk;
            }
        }
        __syncthreads();
        ib ^= 1;
    }
}

// ---------------- K3: MFMA logits + fixed-shift LSE - diag (R8 exact) ----------
// grid (2, Pp): sel = blockIdx.x; 512 threads = 8 waves; wave w rows w*32..+31.
__global__ __launch_bounds__(512) void logits_mfma_kernel(
    const u16* __restrict__ f_bf,
    const u16* __restrict__ pred, const u16* __restrict__ pos,
    float* __restrict__ partial)
{
    __shared__ u16 lds[Nn * Dd];   // 64 KB swizzled pos[p] tile
    const int tid = threadIdx.x;
    const int sel = blockIdx.x;
    const int p = blockIdx.y;
    const int w = tid >> 6;
    const int l = tid & 63;
    const int r0 = w * 32;

    {
        const uint4* src = reinterpret_cast<const uint4*>(pos + (size_t)p * (Nn * Dd));
#pragma unroll
        for (int it = 0; it < 8; ++it) {
            int j = tid + 512 * it;
            int row = j >> 4;
            int colb = (j & 15) << 4;
            uint4 v = src[j];
            *reinterpret_cast<uint4*>((char*)lds + row * 256 + (colb ^ ((row & 7) << 4))) = v;
        }
    }

    const u16* Abase = sel ? (pred + (size_t)p * (Nn * Dd)) : f_bf;
    bf16x8 A[2][4];
    {
        const int arow = l & 15;
        const int acol = (l >> 4) << 4;
#pragma unroll
        for (int rt = 0; rt < 2; ++rt)
#pragma unroll
            for (int kk = 0; kk < 4; ++kk) {
                const char* ap = (const char*)Abase
                               + (size_t)(r0 + rt * 16 + arow) * 256 + kk * 64 + acol;
                A[rt][kk] = *reinterpret_cast<const bf16x8*>(ap);
            }
    }

    __syncthreads();

    const float L2E = 1.4426950408889634f;
    float s_[2][4];
    float dg[2][4];
#pragma unroll
    for (int rt = 0; rt < 2; ++rt)
#pragma unroll
        for (int r = 0; r < 4; ++r) { s_[rt][r] = 0.f; dg[rt][r] = 0.f; }

    const int mcol = l & 15;
    const int bcol = (l >> 4) << 4;

    for (int ct = 0; ct < 16; ++ct) {
        bf16x8 B[4];
        const int mrow = ct * 16 + mcol;
#pragma unroll
        for (int kk = 0; kk < 4; ++kk) {
            int cb = kk * 64 + bcol;
            B[kk] = *reinterpret_cast<const bf16x8*>(
                (const char*)lds + mrow * 256 + (cb ^ ((mrow & 7) << 4)));
        }
#pragma unroll
        for (int rt = 0; rt < 2; ++rt) {
            f32x4 acc = {0.f, 0.f, 0.f, 0.f};
#pragma unroll
            for (int kk = 0; kk < 4; ++kk)
                acc = __builtin_amdgcn_mfma_f32_16x16x32_bf16(A[rt][kk], B[kk], acc, 0, 0, 0);
            const bool isdg_ct = (ct == ((r0 >> 4) + rt));
#pragma unroll
            for (int r = 0; r < 4; ++r) {
                float v = acc[r];
                s_[rt][r] += __builtin_amdgcn_exp2f(fmaf(v, L2E, -64.f));
                if (isdg_ct && ((l & 15) == (((l >> 4) << 2) + r))) dg[rt][r] = v;
            }
        }
    }

    float local = 0.f;
#pragma unroll
    for (int rt = 0; rt < 2; ++rt)
#pragma unroll
        for (int r = 0; r < 4; ++r) {
            float s = s_[rt][r];
            s += __shfl_xor(s, 1);
            s += __shfl_xor(s, 2);
            s += __shfl_xor(s, 4);
            s += __shfl_xor(s, 8);
            if ((l & 15) == (((l >> 4) << 2) + r))
                local += 0.6931471805599453f * (64.f + __log2f(s)) - dg[rt][r];
        }

    __syncthreads();
    float* red = reinterpret_cast<float*>(lds);
    red[tid] = local;
    __syncthreads();
    for (int k = 256; k > 0; k >>= 1) {
        if (tid < k) red[tid] += red[tid + k];
        __syncthreads();
    }
    if (tid == 0) partial[p * 2 + sel] = red[0];
}

// ---------------- K4: deterministic final reduce ----------------
__global__ __launch_bounds__(256) void reduce_kernel(
    const float* __restrict__ partial, float* __restrict__ out)
{
    __shared__ float red[256];
    float s = 0.f;
    for (int i = threadIdx.x; i < 2 * Pp; i += 256) s += partial[i];
    red[threadIdx.x] = s;
    __syncthreads();
    for (int k = 128; k > 0; k >>= 1) {
        if (threadIdx.x < k) red[threadIdx.x] += red[threadIdx.x + k];
        __syncthreads();
    }
    if (threadIdx.x == 0) out[0] = red[0] * (1.0f / (Pp * (float)Nn));
}

extern "C" void kernel_launch(void* const* d_in, const int* in_sizes, int n_in,
                              void* d_out, int out_size, void* d_ws, size_t ws_size,
                              hipStream_t stream)
{
    const float* f   = (const float*)d_in[0];
    const float* x_t = (const float*)d_in[1];
    const float* x_p = (const float*)d_in[2];
    const float* m_t = (const float*)d_in[3];
    const float* m_p = (const float*)d_in[4];
    const float* c_t = (const float*)d_in[5];
    const float* c_p = (const float*)d_in[6];
    const float* W   = (const float*)d_in[7];
    const float* b   = (const float*)d_in[8];

    char* ws = (char*)d_ws;
    const size_t SLAB = (size_t)Pp * Nn * Dd;     // 9,011,200 elems

    float* bias_t = (float*)ws;                          // 131072 B
    float* bias_p = bias_t + Nn * Dd;                    // 131072 B
    u16* f_bf = (u16*)(ws + 262144);                     // 65536 B
    u16* WlT  = f_bf + Nn * Dd;                          // 32768 B
    u16* pred = (u16*)(ws + 360448);
    u16* pos  = pred + SLAB;
    float* partial = (float*)(pos + SLAB);

    bias_kernel<<<dim3(Nn * Dd / 256), 256, 0, stream>>>(m_t, m_p, c_t, c_p, W, b, f,
                                                         bias_t, bias_p, f_bf, WlT);
    join_dbuf_kernel<<<dim3(2, Nn), 512, 0, stream>>>(x_t, x_p, WlT, bias_t, bias_p,
                                                      pred, pos);
    logits_mfma_kernel<<<dim3(2, Pp), 512, 0, stream>>>(f_bf, pred, pos, partial);
    reduce_kernel<<<1, 256, 0, stream>>>(partial, (float*)d_out);
}